// Round 9
// baseline (53.235 us; speedup 1.0000x reference)
//
#include <hip/hip_runtime.h>
#include <math.h>

#define N0v 128
#define B1v 16
#define B2v 16
#define N1v 2048
#define N2v 32768
#define TOTALv 34944
#define BATCHv 1024
#define NEGV -100000000.0f

typedef __attribute__((ext_vector_type(4))) float f32x4;

// System-scope non-temporal stores: sc0 sc1 nt -> no-allocate in L2 AND the
// memory-side Infinity Cache (goal: stop the 140MB output stream from
// evicting the 143MB read-only input out of the 256MB MALL).
__device__ __forceinline__ void nt_store4(f32x4 v, f32x4* p) {
    asm volatile("global_store_dwordx4 %0, %1, off sc0 sc1 nt" :: "v"(p), "v"(v));
}
__device__ __forceinline__ void nt_store1(float v, float* p) {
    asm volatile("global_store_dword %0, %1, off sc0 sc1 nt" :: "v"(p), "v"(v));
}

// One block (1024 threads) per row, R6 structure: header resolves
// pred0/pred1/S0/S1/Sg1/Sg2 from the 9KB prefix; out2 (128KB) streams
// through a depth-2 pipeline (cached load next / exp current / NT store
// current). Loss folded in via one atomicAdd per block (loss slot zeroed
// by hipMemsetAsync in kernel_launch).
__global__ __launch_bounds__(1024, 8) void row_kernel(
    const float* __restrict__ outs, const int* __restrict__ labels,
    float* __restrict__ out, float* __restrict__ loss_out)
{
    const int b   = blockIdx.x;
    const int tid = threadIdx.x;
    const int wid = tid >> 6, lane = tid & 63;
    const float* rowp = outs + (size_t)b * TOTALv;
    float*       orow = out  + (size_t)b * TOTALv;
    const f32x4* rv4 = reinterpret_cast<const f32x4*>(rowp);
    f32x4*       ov4 = reinterpret_cast<f32x4*>(orow);
    const f32x4  neg4 = {NEGV, NEGV, NEGV, NEGV};

    __shared__ float sm_gsum[128];
    __shared__ int   sm_gidx[128];
    __shared__ float s_wmax[2]; __shared__ int s_wmi[2];
    __shared__ float s_red[16][3];
    __shared__ int   s_i[2];
    __shared__ float s_loss[2];   // loss_partial, need_logS2 flag

    const int lab0 = labels[b * 3 + 0];
    const int lab1 = labels[b * 3 + 1];
    const int lab2 = labels[b * 3 + 2];

    // ---------------- header loads + first out2 chunk (cached) ----------------
    float v0 = 0.f;
    if (tid < N0v) v0 = rowp[tid];
    f32x4 a = {0.f, 0.f, 0.f, 0.f};
    if (tid < 512) a = rv4[32 + tid];              // out1: f4 [32,544)
    const f32x4* b2 = rv4 + 544;                   // out2: 8192 f4
    f32x4*       o2 = ov4 + 544;
    f32x4 cur = b2[tid];                           // first stream chunk
    float eg2 = 0.f;
    if (tid < 16) eg2 = rowp[N0v + N1v + lab1 * B2v + tid];
    float t0 = 0.f, t1 = 0.f, t2 = 0.f;
    if (tid == 0) { t0 = rowp[lab0]; t1 = rowp[N0v + lab1]; t2 = rowp[N0v + N1v + lab2]; }
    __builtin_amdgcn_sched_barrier(0);

    // ------- out1 (tid<512): exps + per-group(16) argmax & sumexp -------
    float s1 = 0.f;
    if (tid < 512) {
        s1 = __expf(a.x) + __expf(a.y) + __expf(a.z) + __expf(a.w);
        float gm = a.x; int gi = 0;
        if (a.y > gm) { gm = a.y; gi = 1; }
        if (a.z > gm) { gm = a.z; gi = 2; }
        if (a.w > gm) { gm = a.w; gi = 3; }
        gi += (tid & 3) * 4;
        float gs = s1;
        float ov = __shfl_xor(gm, 1); int oi = __shfl_xor(gi, 1);
        gs += __shfl_xor(gs, 1);
        if (ov > gm || (ov == gm && oi < gi)) { gm = ov; gi = oi; }
        ov = __shfl_xor(gm, 2); oi = __shfl_xor(gi, 2);
        gs += __shfl_xor(gs, 2);
        if (ov > gm || (ov == gm && oi < gi)) { gm = ov; gi = oi; }
        if ((tid & 3) == 0) { sm_gsum[tid >> 2] = gs; sm_gidx[tid >> 2] = gi; }
    }

    // ------- pred0: argmax over out0 (waves 0,1) -------
    if (tid < N0v) {
        float mv = v0; int mi = tid;
        #pragma unroll
        for (int off = 32; off; off >>= 1) {
            float ovv = __shfl_down(mv, off);
            int   oii = __shfl_down(mi, off);
            if (ovv > mv || (ovv == mv && oii < mi)) { mv = ovv; mi = oii; }
        }
        if (lane == 0) { s_wmax[wid] = mv; s_wmi[wid] = mi; }
    }

    // ------- Sg2: 16-wide sumexp at lab1 (lands in tid0 register) -------
    if (tid < 16) {
        eg2 = __expf(eg2);
        #pragma unroll
        for (int off = 8; off; off >>= 1) eg2 += __shfl_xor(eg2, off);
    }

    // ------- S0 (shiftless) + S1 wave reductions -------
    float r0 = (tid < N0v) ? __expf(v0) : 0.f;
    #pragma unroll
    for (int off = 32; off; off >>= 1) {
        r0 += __shfl_down(r0, off);
        s1 += __shfl_down(s1, off);
    }
    if (lane == 0) { s_red[wid][0] = r0; s_red[wid][1] = s1; }

    __syncthreads();   // barrier #1

    if (tid == 0) {
        float m0 = s_wmax[0]; int p0 = s_wmi[0];
        if (s_wmax[1] > m0 || (s_wmax[1] == m0 && s_wmi[1] < p0)) { m0 = s_wmax[1]; p0 = s_wmi[1]; }
        const int p1i = sm_gidx[p0];
        s_i[0] = p0; s_i[1] = p1i;
        float S0 = 0.f, S1 = 0.f;
        #pragma unroll
        for (int w = 0; w < 16; ++w) { S0 += s_red[w][0]; S1 += s_red[w][1]; }
        const float Sg1 = sm_gsum[lab0];
        const int r1 = lab1 - lab0 * B1v;
        const bool found0 = (p0 != lab0);
        const bool found1 = found0 || (p1i != r1);
        const float loss0 = __logf(S0) - t0;
        const float loss1 = (found0 ? __logf(S1) : __logf(Sg1)) - t1;
        s_loss[0] = loss0 + loss1 - t2 + (found1 ? 0.f : __logf(eg2));
        s_loss[1] = found1 ? 1.f : 0.f;
    }

    __syncthreads();   // barrier #2
    const int pred0 = s_i[0];
    const int pred1 = pred0 * B1v + s_i[1];

    // ------- out0/out1 masked NT stores (9KB) -------
    if (tid < 512) {
        nt_store4(((tid >> 2) == pred0) ? a : neg4, &ov4[32 + tid]);
        if (tid < N0v) nt_store1(v0, &orow[tid]);
    }

    // ------- out2 stream: depth-2 pipeline, 8 chunks (cached in, NT out) -------
    float s2 = 0.f;
    int idx = tid;
    #pragma unroll
    for (int it = 0; it < 7; ++it) {
        const f32x4 nxt = b2[idx + 1024];
        s2 += __expf(cur.x) + __expf(cur.y) + __expf(cur.z) + __expf(cur.w);
        nt_store4(((idx >> 2) == pred1) ? cur : neg4, &o2[idx]);
        cur = nxt; idx += 1024;
    }
    s2 += __expf(cur.x) + __expf(cur.y) + __expf(cur.z) + __expf(cur.w);
    nt_store4(((idx >> 2) == pred1) ? cur : neg4, &o2[idx]);

    // ------- final S2 reduction + loss atomic -------
    #pragma unroll
    for (int off = 32; off; off >>= 1) s2 += __shfl_down(s2, off);
    if (lane == 0) s_red[wid][2] = s2;
    __syncthreads();   // barrier #3
    if (tid == 0) {
        float S2 = 0.f;
        #pragma unroll
        for (int w = 0; w < 16; ++w) S2 += s_red[w][2];
        atomicAdd(loss_out, s_loss[0] + s_loss[1] * __logf(S2));
    }

    // inline-asm stores are not vmcnt-tracked by the compiler: drain before exit
    asm volatile("s_waitcnt vmcnt(0)" ::: "memory");
}

extern "C" void kernel_launch(void* const* d_in, const int* in_sizes, int n_in,
                              void* d_out, int out_size, void* d_ws, size_t ws_size,
                              hipStream_t stream) {
    const float* outs   = (const float*)d_in[0];
    const int*   labels = (const int*)d_in[1];
    float*       out    = (float*)d_out;
    float*       loss   = out + (size_t)BATCHv * TOTALv;

    hipMemsetAsync((void*)loss, 0, sizeof(float), stream);
    row_kernel<<<BATCHv, 1024, 0, stream>>>(outs, labels, out, loss);
}